// Round 13
// baseline (44.349 us; speedup 1.0000x reference)
//
#include <hip/hip_runtime.h>
#include <math.h>

#define W_ 128
#define H_ 96
#define C_ 128
#define HW_ (H_ * W_)          // 12288
#define K_ 81
#define FLOW_ELEMS (2 * 2 * H_ * W_)   // 49152
#define PLANE_F (2 * C_ * H_ * W_)     // floats per repacked tensor: 3145728

typedef __fp16 half2_t __attribute__((ext_vector_type(2)));

__device__ __forceinline__ half2_t pkrtz(float a, float b) {
    return __builtin_amdgcn_cvt_pkrtz(a, b);   // v_cvt_pkrtz_f16_f32
}

__device__ __forceinline__ float dot2(half2_t a, unsigned bw, float c) {
    const half2_t b = __builtin_bit_cast(half2_t, bw);
#if __has_builtin(__builtin_amdgcn_fdot2)
    return __builtin_amdgcn_fdot2(a, b, c, false);   // v_dot2_f32_f16
#else
    return fmaf((float)a.x, (float)b.x, fmaf((float)a.y, (float)b.y, c));
#endif
}

// ---------------- prep: repack [C][H][W] -> [H][C][W] (exact f32 copy) ----------------
// Pure index remap; lane keeps its x-pair. Block = (tensor, b, y): moves 64 KB.
// Grid = 384 blocks x 256 threads.
__global__ __launch_bounds__(256) void repack_kernel(const float* __restrict__ f0,
                                                     const float* __restrict__ f1,
                                                     float* __restrict__ f0t,
                                                     float* __restrict__ f1t) {
    const int blk = blockIdx.x;          // 0..383
    const int t = blk & 1;
    const int b = (blk >> 1) & 1;
    const int y = blk >> 2;              // 0..95

    const float* src = (t ? f1 : f0) + ((size_t)b * C_ * H_) * W_ + (size_t)y * W_;
    float* dst = (t ? f1t : f0t) + ((size_t)(b * H_ + y) * C_) * W_;

    const int lane = threadIdx.x & 63;
    const int sub = threadIdx.x >> 6;    // 0..3

#pragma unroll
    for (int it = 0; it < 32; ++it) {
        const int c = it * 4 + sub;
        const float2 v = *(const float2*)(src + (size_t)c * HW_ + 2 * lane);
        *(float2*)(dst + (size_t)c * W_ + 2 * lane) = v;
    }
}

// ---------------- corr kernel (R12-verified, channel stride now W_) ----------------
// One 64-thread block (= one wave) per (b, y0, dg), dg in 0..8 -> dy = dg-4.
// Wave accumulates ALL 128 channels for halo row r = y0+dg-4, writes disjoint
// k-slice [dg*9, dg*9+9) for all 128 px of row y0. f16 packed dot2 inner loop.
// Inputs are the repacked [b][y][c][x] tensors: a wave's working set is one
// CONTIGUOUS 64 KB block per tensor (TLB/L1/L2-friendly).
// Lane owns pixels x = 2*lane, 2*lane+1. Grid = 1728 blocks (8 XCD chunks x 216).
__global__ __launch_bounds__(64) void corr_kernel(const float* __restrict__ f0t,
                                                  const float* __restrict__ f1t,
                                                  float* __restrict__ corr) {
    __shared__ unsigned lds[8][136];   // 8 c-pairs x 136 halo cols (4352 B)

    const int lane = threadIdx.x;

    // XCD-bijective swizzle: 1728 = 8 * 216
    const int L = (blockIdx.x & 7) * 216 + (blockIdx.x >> 3);
    const int dg = L % 9;
    const int rid = L / 9;               // 0..191
    const int y0 = rid % H_;
    const int b  = rid / H_;
    const int r  = y0 + dg - 4;          // halo row in f1 (may be OOB)
    const bool rok = (r >= 0) && (r < H_);

    // staging: lane q stages quad q covering f1 columns q*4-4 .. q*4-1;
    // word w holds column w-4. Quads 0 and 33 are fully OOB -> zeros.
    const int q = lane;
    const bool qok = rok && (q >= 1) && (q <= 32);
    const float* f0p = f0t + ((size_t)(b * H_ + y0) * C_) * W_ + 2 * lane;
    const float* f1p = f1t + ((size_t)(b * H_ + (rok ? r : 0)) * C_) * W_ + (q * 4 - 4);

    float acc0[9], acc1[9];
#pragma unroll
    for (int j = 0; j < 9; ++j) { acc0[j] = 0.f; acc1[j] = 0.f; }

    for (int ck = 0; ck < 8; ++ck) {
        // ---- load 16 channels (f0 px-pair + f1 col-quad); stride is now W_ ----
        float4 v[16];
        float2 g[16];
#pragma unroll
        for (int cc = 0; cc < 16; ++cc) {
            const size_t co = (size_t)(ck * 16 + cc) * W_;
            g[cc] = *(const float2*)(f0p + co);
            float4 t = make_float4(0.f, 0.f, 0.f, 0.f);
            if (qok) t = *(const float4*)(f1p + co);
            v[cc] = t;
        }

        // ---- pack channel pairs to f16x2 ----
        half2_t a0[8], a1[8];      // f0 for px 2*lane, 2*lane+1
        uint4 pw[8];               // f1: 4 packed cols per c-pair
#pragma unroll
        for (int j = 0; j < 8; ++j) {
            a0[j] = pkrtz(g[2 * j].x, g[2 * j + 1].x);
            a1[j] = pkrtz(g[2 * j].y, g[2 * j + 1].y);
            pw[j].x = __builtin_bit_cast(unsigned, pkrtz(v[2 * j].x, v[2 * j + 1].x));
            pw[j].y = __builtin_bit_cast(unsigned, pkrtz(v[2 * j].y, v[2 * j + 1].y));
            pw[j].z = __builtin_bit_cast(unsigned, pkrtz(v[2 * j].z, v[2 * j + 1].z));
            pw[j].w = __builtin_bit_cast(unsigned, pkrtz(v[2 * j].w, v[2 * j + 1].w));
        }

        // ---- stage to LDS (fence-only; 1-wave block, DS-pipe order) ----
        __builtin_amdgcn_sched_barrier(0);
        if (q < 34) {
#pragma unroll
            for (int j = 0; j < 8; ++j)
                *(uint4*)&lds[j][q * 4] = pw[j];
        }
        __builtin_amdgcn_sched_barrier(0);

        // ---- consume: per c-pair, 10 packed cols feed 18 dot2 ----
#pragma unroll
        for (int j = 0; j < 8; ++j) {
            const uint2* row = (const uint2*)(&lds[j][0]) + lane;
            const uint2 w0 = row[0], w1 = row[1], w2 = row[2],
                        w3 = row[3], w4 = row[4];
            const unsigned vv[10] = {w0.x, w0.y, w1.x, w1.y, w2.x,
                                     w2.y, w3.x, w3.y, w4.x, w4.y};
#pragma unroll
            for (int dx = 0; dx < 9; ++dx) {
                acc0[dx] = dot2(a0[j], vv[dx], acc0[dx]);
                acc1[dx] = dot2(a1[j], vv[dx + 1], acc1[dx]);
            }
        }
    }

    // disjoint k-slice writeout; OOB-row waves naturally wrote acc==0
    float* cb = corr + ((size_t)b * HW_ + (size_t)y0 * W_ + 2 * lane) * K_ + dg * 9;
#pragma unroll
    for (int j = 0; j < 9; ++j) cb[j] = acc0[j];
#pragma unroll
    for (int j = 0; j < 9; ++j) cb[K_ + j] = acc1[j];
}

// Kernel 3: scale by 1/sqrt(128), softmax over K in-place, prob + flow.
// (verified in R5; unchanged)
__global__ __launch_bounds__(256) void softmax_kernel(float* __restrict__ out) {
    const int t = threadIdx.x;
    const int wave = t >> 6, lane = t & 63;
    const int px = (blockIdx.x << 2) + wave;      // 0 .. 24575
    const int b = px / HW_;
    const int pl = px - b * HW_;
    const int y = pl >> 7, x = pl & 127;

    float* corr = out + FLOW_ELEMS + (size_t)px * K_;
    const float scale = 0.08838834764831845f;     // 1/sqrt(128)

    const bool has1 = lane < (K_ - 64);           // lane < 17
    float v0 = corr[lane] * scale;
    float v1 = has1 ? corr[lane + 64] * scale : -1e30f;

    float m = fmaxf(v0, v1);
#pragma unroll
    for (int off = 32; off; off >>= 1) m = fmaxf(m, __shfl_xor(m, off));

    float e0 = __expf(v0 - m);
    float e1 = has1 ? __expf(v1 - m) : 0.f;
    float s = e0 + e1;
#pragma unroll
    for (int off = 32; off; off >>= 1) s += __shfl_xor(s, off);

    const float inv = 1.f / s;
    const float p0 = e0 * inv;
    const float p1 = e1 * inv;

    corr[lane] = p0;
    if (has1) corr[lane + 64] = p1;

    float fx = p0 * (float)(lane % 9 - 4) + p1 * (float)((lane + 64) % 9 - 4);
    float fy = p0 * (float)(lane / 9 - 4) + p1 * (float)((lane + 64) / 9 - 4);
#pragma unroll
    for (int off = 32; off; off >>= 1) {
        fx += __shfl_xor(fx, off);
        fy += __shfl_xor(fy, off);
    }

    if (lane == 0) {
        out[((size_t)(b * 2 + 0) * H_ + y) * W_ + x] = fx;
        out[((size_t)(b * 2 + 1) * H_ + y) * W_ + x] = fy;
    }
}

extern "C" void kernel_launch(void* const* d_in, const int* in_sizes, int n_in,
                              void* d_out, int out_size, void* d_ws, size_t ws_size,
                              hipStream_t stream) {
    (void)in_sizes; (void)n_in; (void)ws_size; (void)out_size;
    const float* f0 = (const float*)d_in[0];
    const float* f1 = (const float*)d_in[1];
    float* out = (float*)d_out;
    float* f0t = (float*)d_ws;               // 12.58 MB
    float* f1t = (float*)d_ws + PLANE_F;     // 12.58 MB

    repack_kernel<<<384, 256, 0, stream>>>(f0, f1, f0t, f1t);
    corr_kernel<<<1728, 64, 0, stream>>>(f0t, f1t, out + FLOW_ELEMS);
    softmax_kernel<<<6144, 256, 0, stream>>>(out);
}

// Round 14
// 37.774 us; speedup vs baseline: 1.1741x; 1.1741x over previous
//
#include <hip/hip_runtime.h>
#include <math.h>

#define W_ 128
#define H_ 96
#define C_ 128
#define HW_ (H_ * W_)          // 12288
#define K_ 81
#define FLOW_ELEMS (2 * 2 * H_ * W_)   // 49152
#define XPAD 144               // f1h padded cols: xp = x+4, zeros outside [4,131]
#define CP 64                  // channel pairs (u32 words per col)

typedef __fp16 f16x8 __attribute__((ext_vector_type(8)));
typedef float  f32x4 __attribute__((ext_vector_type(4)));

__device__ __forceinline__ unsigned pack_pair(float a, float b) {
    return __builtin_bit_cast(unsigned, __builtin_amdgcn_cvt_pkrtz(a, b));
}

// ---------------- repack f1: [b][c][y][x] f32 -> [b][y][xp][c] f16 ----------------
// One block per (b, y). LDS transpose x<->c; halo cols zeroed.
__global__ __launch_bounds__(256) void repack_kernel(const float* __restrict__ f1,
                                                     unsigned* __restrict__ f1h32) {
    __shared__ unsigned lds[128 * 67];   // [x][cp], stride 67 (bank-spread)
    const int t = threadIdx.x;
    const int wid = t >> 6, lane = t & 63;
    const int L = (blockIdx.x & 7) * 24 + (blockIdx.x >> 3);   // 192 = 8*24
    const int y = L % H_;
    const int b = L / H_;
    const float* src = f1 + (size_t)b * C_ * HW_ + (size_t)y * W_;

    for (int it = 0; it < 16; ++it) {
        const int cp = it * 4 + wid;     // 0..63
        const float2 v0 = *(const float2*)(src + (size_t)(2 * cp) * HW_ + 2 * lane);
        const float2 v1 = *(const float2*)(src + (size_t)(2 * cp + 1) * HW_ + 2 * lane);
        lds[(2 * lane) * 67 + cp]     = pack_pair(v0.x, v1.x);
        lds[(2 * lane + 1) * 67 + cp] = pack_pair(v0.y, v1.y);
    }
    __syncthreads();

    unsigned* dst = f1h32 + (size_t)(b * H_ + y) * XPAD * CP;
    for (int it = 0; it < 32; ++it) {
        const int flat = it * 256 + t;
        const int x = flat >> 6, cp = flat & 63;
        dst[(size_t)(x + 4) * CP + cp] = lds[x * 67 + cp];
    }
    // halo: xp in {0..3} U {132..143} -> zero
    for (int i = t; i < 16 * CP; i += 256) {
        const int col = i >> 6, cp = i & 63;
        const int xp = (col < 4) ? col : 128 + col;
        dst[(size_t)xp * CP + cp] = 0u;
    }
}

// ---------------- fused MFMA corr + softmax + flow ----------------
// Block = 256 thr (4 waves) per (b, y0, xhalf): 64 pixels. Wave wid owns the
// 16-px tile at px0 = xh*64 + wid*16. For each dy: D = f0_tile(16x128) x
// f1h_cols(128x32) via 8 mfma_f32_16x16x32_f16; band dx=j-i in [0,8] goes to
// corr_lds. Then per-px softmax + flow + coalesced prob writeout.
__global__ __launch_bounds__(256) void fused_kernel(const float* __restrict__ f0,
                                                    const __fp16* __restrict__ f1h,
                                                    float* __restrict__ out) {
    __shared__ float corr_lds[64][85];   // stride 85: 2-way max on column reads
    __shared__ float mbuf[64], ibuf[64];

    const int t = threadIdx.x;
    const int wid = t >> 6, l = t & 63;
    const int L = (blockIdx.x & 7) * 48 + (blockIdx.x >> 3);   // 384 = 8*48
    const int xh = L & 1;
    const int y0 = (L >> 1) % H_;
    const int b  = L / (2 * H_);
    const int px0 = xh * 64 + wid * 16;  // absolute tile base x

    for (int i = t; i < 64 * 85; i += 256) (&corr_lds[0][0])[i] = 0.f;
    __syncthreads();

    // ---- A-frags straight from f32 f0: lane row = l&15, k = (l>>4)*8 + j ----
    f16x8 a[4];
    {
        const int px = px0 + (l & 15);
        const float* f0p = f0 + (size_t)b * C_ * HW_ + (size_t)y0 * W_ + px;
#pragma unroll
        for (int kk = 0; kk < 4; ++kk) {
            f16x8 av;
#pragma unroll
            for (int j = 0; j < 8; ++j)
                av[j] = (__fp16)f0p[(size_t)(kk * 32 + (l >> 4) * 8 + j) * HW_];
            a[kk] = av;
        }
    }

    for (int dy = 0; dy < 9; ++dy) {
        const int r = y0 + dy - 4;
        if (r < 0 || r >= H_) continue;            // band stays zero (pre-zeroed LDS)
        const __fp16* bp = f1h + (size_t)(b * H_ + r) * XPAD * C_;
        const int co = (l >> 4) * 8;

        f32x4 accA = {0.f, 0.f, 0.f, 0.f}, accB = {0.f, 0.f, 0.f, 0.f};
#pragma unroll
        for (int kk = 0; kk < 4; ++kk) {
            const f16x8 bA = *(const f16x8*)(bp + (size_t)(px0 + (l & 15)) * C_ + kk * 32 + co);
            accA = __builtin_amdgcn_mfma_f32_16x16x32_f16(a[kk], bA, accA, 0, 0, 0);
            const f16x8 bB = *(const f16x8*)(bp + (size_t)(px0 + 16 + (l & 15)) * C_ + kk * 32 + co);
            accB = __builtin_amdgcn_mfma_f32_16x16x32_f16(a[kk], bB, accB, 0, 0, 0);
        }

        // ---- band extraction: C col=l&15 (j), row=(l>>4)*4+reg (i); dx = j-i ----
#pragma unroll
        for (int h = 0; h < 2; ++h) {
            const f32x4 acc = h ? accB : accA;
#pragma unroll
            for (int rg = 0; rg < 4; ++rg) {
                const int i = (l >> 4) * 4 + rg;
                const int j = h * 16 + (l & 15);
                const int dxw = j - i;
                if (dxw >= 0 && dxw <= 8)
                    corr_lds[wid * 16 + i][dy * 9 + dxw] = acc[rg];
            }
        }
    }
    __syncthreads();

    const float scale = 0.08838834764831845f;     // 1/sqrt(128)

    // ---- pass 1: thread-per-px softmax + flow ----
    if (t < 64) {
        float m = -1e30f;
#pragma unroll 9
        for (int k = 0; k < K_; ++k) m = fmaxf(m, corr_lds[t][k] * scale);
        float s = 0.f, fx = 0.f, fy = 0.f;
#pragma unroll 9
        for (int k = 0; k < K_; ++k) {
            const float e = __expf(corr_lds[t][k] * scale - m);
            s += e;
            fx += e * (float)(k % 9 - 4);
            fy += e * (float)(k / 9 - 4);
        }
        const float inv = 1.f / s;
        mbuf[t] = m;
        ibuf[t] = inv;
        const int x = xh * 64 + t;
        out[((size_t)(b * 2 + 0) * H_ + y0) * W_ + x] = fx * inv;
        out[((size_t)(b * 2 + 1) * H_ + y0) * W_ + x] = fy * inv;
    }
    __syncthreads();

    // ---- pass 2: coalesced match_prob writeout ----
    float* mp = out + FLOW_ELEMS + ((size_t)b * HW_ + (size_t)y0 * W_ + xh * 64) * K_;
    for (int f = t; f < 64 * K_; f += 256) {
        const int px = f / K_;
        const int k = f - px * K_;
        mp[f] = __expf(corr_lds[px][k] * scale - mbuf[px]) * ibuf[px];
    }
}

extern "C" void kernel_launch(void* const* d_in, const int* in_sizes, int n_in,
                              void* d_out, int out_size, void* d_ws, size_t ws_size,
                              hipStream_t stream) {
    (void)in_sizes; (void)n_in; (void)out_size; (void)ws_size;
    const float* f0 = (const float*)d_in[0];
    const float* f1 = (const float*)d_in[1];
    float* out = (float*)d_out;
    unsigned* f1h32 = (unsigned*)d_ws;   // 2*96*144*64 u32 = 7.08 MB

    repack_kernel<<<192, 256, 0, stream>>>(f1, f1h32);
    fused_kernel<<<384, 256, 0, stream>>>(f0, (const __fp16*)d_ws, out);
}